// Round 8
// baseline (272.509 us; speedup 1.0000x reference)
//
#include <hip/hip_runtime.h>
#include <math.h>

#define Bn 16
#define Gn 2048
#define Cn 128
#define Kn 16
#define SCAP 40    // u8 survivor slice cap per (query,sub); mean ~10.7, P(ovf)~1e-7

__device__ __forceinline__ float med3f(float a, float b, float c) {
#if __has_builtin(__builtin_amdgcn_fmed3f)
    return __builtin_amdgcn_fmed3f(a, b, c);
#else
    return fmaxf(fminf(a, b), fminf(fmaxf(a, b), c));
#endif
}

// BIT-IDENTICAL everywhere (self-consistent fp ranking incl. tie detection).
__device__ __forceinline__ float dist2(const float4 me, const float4 p) {
    float dot = fmaf(me.z, p.z, fmaf(me.y, p.y, me.x * p.x));
    return fmaf(-2.0f, dot, me.w + p.w);
}

__device__ __forceinline__ void ins16(float (&d)[16], float v) {
    float prev = d[0];
    d[0] = fminf(d[0], v);
    #pragma unroll
    for (int t = 1; t < 16; ++t) { float cur = d[t]; d[t] = med3f(v, prev, cur); prev = cur; }
}

__device__ __forceinline__ void bsort16(float (&x)[16]) {
    #pragma unroll
    for (int k = 8; k; k >>= 1) {
        #pragma unroll
        for (int t = 0; t < 16; ++t)
            if (!(t & k)) {
                float lo = fminf(x[t], x[t + k]);
                float hi = fmaxf(x[t], x[t + k]);
                x[t] = lo; x[t + k] = hi;
            }
    }
}

__device__ __forceinline__ void bmerge(float (&da)[16], const float (&db)[16]) {
    float x[16];
    #pragma unroll
    for (int t = 0; t < 16; ++t) x[t] = fminf(da[t], db[15 - t]);
    bsort16(x);
    #pragma unroll
    for (int t = 0; t < 16; ++t) da[t] = x[t];
}

__device__ __forceinline__ void merge8(float (&d)[16]) {
    #pragma unroll
    for (int m = 1; m < 8; m <<= 1) {
        float e[16];
        #pragma unroll
        for (int t = 0; t < 16; ++t) e[t] = __shfl_xor(d[t], m);
        float x[16];
        #pragma unroll
        for (int t = 0; t < 16; ++t) x[t] = fminf(d[t], e[15 - t]);
        bsort16(x);
        #pragma unroll
        for (int t = 0; t < 16; ++t) d[t] = x[t];
    }
}

// ---------------------------------------------------------------------------
// Kernel 1: KNN top-16 (unchanged from R7): sample->filter->select, private
// u8 survivor slices. 1024 blocks; 32 queries/block.
// ---------------------------------------------------------------------------
__global__ __launch_bounds__(256) void knn_kernel(const float* __restrict__ xyz,
                                                  int* __restrict__ idx_out) {
    __shared__ float4 pts[Gn];                      // 32 KB
    __shared__ unsigned char sbuf[256 * SCAP];      // 10 KB
    __shared__ int outb[32 * 16];                   // 2 KB
    __shared__ int tieb[32 * 16];                   // 2 KB

    const int x     = blockIdx.x;
    const int b     = (x & 7) | (((x >> 3) & 1) << 3);
    const int chunk = x >> 4;
    const int tid   = threadIdx.x;
    const int lane  = tid & 63;
    const int w     = tid >> 6;
    const int sub   = lane & 7;
    const int q     = w * 8 + (lane >> 3);
    const int g     = chunk * 32 + q;
    const int bs    = (w * 64 + lane) * SCAP;

    const float* xb = xyz + (size_t)b * Gn * 3;
    for (int i = tid; i < Gn; i += 256) {
        float px = xb[i * 3 + 0], py = xb[i * 3 + 1], pz = xb[i * 3 + 2];
        pts[i] = make_float4(px, py, pz, px * px + py * py + pz * pz);
    }
    __syncthreads();

    const float4 me = pts[g];
    const int base = sub << 8;
    const int c    = (37 * sub) & 255;

    float da[16], db[16];
    #pragma unroll
    for (int t = 0; t < 16; ++t) { da[t] = INFINITY; db[t] = INFINITY; }
    for (int j = 0; j < 48; j += 4) {
        float4 p0 = pts[base + ((j + 0 + c) & 255)];
        float4 p1 = pts[base + ((j + 1 + c) & 255)];
        float4 p2 = pts[base + ((j + 2 + c) & 255)];
        float4 p3 = pts[base + ((j + 3 + c) & 255)];
        float v0 = dist2(me, p0), v1 = dist2(me, p1);
        float v2 = dist2(me, p2), v3 = dist2(me, p3);
        ins16(da, v0); ins16(db, v1);
        ins16(da, v2); ins16(db, v3);
    }
    bmerge(da, db);
    merge8(da);
    const float T0 = da[15];

    int cnt = 0;
    for (int j = 0; j < 256; j += 4) {
        int m0 = (j + 0 + c) & 255;
        int m1 = (j + 1 + c) & 255;
        int m2 = (j + 2 + c) & 255;
        int m3 = (j + 3 + c) & 255;
        float v0 = dist2(me, pts[base + m0]);
        float v1 = dist2(me, pts[base + m1]);
        float v2 = dist2(me, pts[base + m2]);
        float v3 = dist2(me, pts[base + m3]);
        if (v0 <= T0) { if (cnt < SCAP) sbuf[bs + cnt] = (unsigned char)m0; cnt++; }
        if (v1 <= T0) { if (cnt < SCAP) sbuf[bs + cnt] = (unsigned char)m1; cnt++; }
        if (v2 <= T0) { if (cnt < SCAP) sbuf[bs + cnt] = (unsigned char)m2; cnt++; }
        if (v3 <= T0) { if (cnt < SCAP) sbuf[bs + cnt] = (unsigned char)m3; cnt++; }
    }
    const int S = (cnt > SCAP) ? SCAP : cnt;

    #pragma unroll
    for (int t = 0; t < 16; ++t) da[t] = INFINITY;
    for (int t = 0; t < S; ++t) {
        float4 p = pts[base + sbuf[bs + t]];
        ins16(da, dist2(me, p));
    }
    merge8(da);
    const float T = da[15];

    int maxc = S;
    #pragma unroll
    for (int m = 1; m < 8; m <<= 1) { int o = __shfl_xor(maxc, m); maxc = (o > maxc) ? o : maxc; }

    const unsigned lowm = (1u << sub) - 1;
    const int shft = lane & 56;
    int nl = 0, nt = 0;
    for (int t = 0; t < maxc; ++t) {
        bool act = (t < S);
        int h = act ? (base + sbuf[bs + t]) : 0;
        float v = dist2(me, pts[h]);
        bool pl = act && (v < T);
        bool pt = act && (v == T);
        unsigned long long ml = __ballot(pl);
        unsigned long long mt = __ballot(pt);
        unsigned gml = (unsigned)(ml >> shft) & 0xFFu;
        unsigned gmt = (unsigned)(mt >> shft) & 0xFFu;
        if (pl) outb[q * 16 + nl + __popc(gml & lowm)] = h;
        if (pt) { int pp = nt + __popc(gmt & lowm); if (pp < 16) tieb[q * 16 + pp] = h; }
        nl += __popc(gml);
        nt += __popc(gmt);
    }
    if (sub == 0) {
        int mfill = nl;
        int need  = 16 - mfill;
        int tc = (nt > 16) ? 16 : nt;
        for (int s = 0; s < need; ++s) {
            int best = 0x7fffffff, bp = -1;
            for (int u = 0; u < tc; ++u) {
                int vv = tieb[q * 16 + u];
                if (vv < best) { best = vv; bp = u; }
            }
            if (bp >= 0) { tieb[q * 16 + bp] = 0x7fffffff; outb[q * 16 + mfill + s] = best; }
        }
    }
    __syncthreads();

    int* op = idx_out + ((size_t)b * Gn + (size_t)chunk * 32) * Kn;
    for (int t = tid; t < 512; t += 256) op[t] = outb[t];
}

// ---------------------------------------------------------------------------
// Kernel 2: gather + L2 pool + 2-layer MLP, scalar-W design.
// 512 blocks x 64 rows; 256 thr; lane = row, wave = 32-col slice.
// W read with wave-uniform addresses -> s_load through scalar K$ (no L1
// thrash, no per-lane W traffic). Inner loop: 1 ds_read_b128 + 128 v_fmac.
// At padded to 133 floats/row: column-major lane access conflict-free.
// ---------------------------------------------------------------------------
__device__ __forceinline__ float gelu_exact(float x) {
    return 0.5f * x * (1.0f + erff(x * 0.70710678118654752440f));
}

__global__ __launch_bounds__(256) void pm_kernel(const float* __restrict__ feat,
                                                 const int* __restrict__ idx,
                                                 const float* __restrict__ W1,
                                                 const float* __restrict__ b1,
                                                 const float* __restrict__ W2,
                                                 const float* __restrict__ b2,
                                                 float* __restrict__ out) {
    __shared__ float At[64 * 133];                  // 34 KB padded rows
    __shared__ int   qidx[64 * 16];                 // 4 KB staged indices

    const int x     = blockIdx.x;                   // 0..511
    const int b     = (x & 7) | (((x >> 3) & 1) << 3);   // XCD-local feat batches
    const int chunk = x >> 4;                       // 0..31 (64-row chunks)
    const int tid   = threadIdx.x;
    const int lane  = tid & 63;
    const int w     = tid >> 6;
    const size_t rowbase = (size_t)b * Gn + (size_t)chunk * 64;

    const int* ip = idx + rowbase * Kn;
    for (int t = tid; t < 1024; t += 256) qidx[t] = ip[t];
    __syncthreads();

    // ---- gather + pool: half-wave per query row, float4 lanes (512B coalesced)
    const float4* fb4 = (const float4*)(feat + (size_t)b * Gn * Cn);
    const int cl = lane & 31;
    for (int pass = 0; pass < 8; ++pass) {
        int qq = w * 16 + pass * 2 + (lane >> 5);   // 0..63
        float4 a = make_float4(0.f, 0.f, 0.f, 0.f);
        #pragma unroll
        for (int half = 0; half < 2; ++half) {
            int hs[8]; float4 f[8];
            #pragma unroll
            for (int k = 0; k < 8; ++k) hs[k] = qidx[qq * 16 + half * 8 + k];
            #pragma unroll
            for (int k = 0; k < 8; ++k) f[k] = fb4[(size_t)hs[k] * 32 + cl];
            #pragma unroll
            for (int k = 0; k < 8; ++k) {
                a.x = fmaf(f[k].x, f[k].x, a.x);
                a.y = fmaf(f[k].y, f[k].y, a.y);
                a.z = fmaf(f[k].z, f[k].z, a.z);
                a.w = fmaf(f[k].w, f[k].w, a.w);
            }
        }
        float4 r = make_float4(sqrtf(a.x), sqrtf(a.y), sqrtf(a.z), sqrtf(a.w));
        *(float4*)&At[qq * 133 + cl * 4] = r;
    }
    __syncthreads();

    // ---- MLP: lane = row (0..63), wave = cols [w*32, w*32+32)
    const int r  = lane;
    const int jb = w * 32;
    float acc[32];

    // layer 1: acc = b1 + At[r,:] @ W1[:, jb:jb+32]  (W via scalar path)
    {
        const float* Wl = W1 + jb;
        #pragma unroll
        for (int j = 0; j < 32; ++j) acc[j] = b1[jb + j];      // wave-uniform
        for (int k0 = 0; k0 < 128; k0 += 4) {
            float4 a4 = *(const float4*)&At[r * 133 + k0];
            const float av[4] = {a4.x, a4.y, a4.z, a4.w};
            #pragma unroll
            for (int kk = 0; kk < 4; ++kk) {
                const float* wr = Wl + (k0 + kk) * Cn;          // wave-uniform addr
                #pragma unroll
                for (int j = 0; j < 32; ++j)
                    acc[j] = fmaf(av[kk], wr[j], acc[j]);
            }
        }
    }
    __syncthreads();                                 // all layer-1 reads of At done
    #pragma unroll
    for (int u = 0; u < 8; ++u) {
        float4 h4;
        h4.x = gelu_exact(acc[4 * u + 0]);
        h4.y = gelu_exact(acc[4 * u + 1]);
        h4.z = gelu_exact(acc[4 * u + 2]);
        h4.w = gelu_exact(acc[4 * u + 3]);
        *(float4*)&At[r * 133 + jb + 4 * u] = h4;    // lane-stride 133: conflict-free
    }
    __syncthreads();

    // layer 2: acc = b2 + h[r,:] @ W2[:, jb:jb+32]
    {
        const float* Wl = W2 + jb;
        #pragma unroll
        for (int j = 0; j < 32; ++j) acc[j] = b2[jb + j];
        for (int k0 = 0; k0 < 128; k0 += 4) {
            float4 a4 = *(const float4*)&At[r * 133 + k0];
            const float av[4] = {a4.x, a4.y, a4.z, a4.w};
            #pragma unroll
            for (int kk = 0; kk < 4; ++kk) {
                const float* wr = Wl + (k0 + kk) * Cn;
                #pragma unroll
                for (int j = 0; j < 32; ++j)
                    acc[j] = fmaf(av[kk], wr[j], acc[j]);
            }
        }
    }
    float4* op = (float4*)(out + (rowbase + r) * Cn + jb);
    #pragma unroll
    for (int u = 0; u < 8; ++u)
        op[u] = make_float4(acc[4 * u + 0], acc[4 * u + 1], acc[4 * u + 2], acc[4 * u + 3]);
}

// ---------------------------------------------------------------------------
extern "C" void kernel_launch(void* const* d_in, const int* in_sizes, int n_in,
                              void* d_out, int out_size, void* d_ws, size_t ws_size,
                              hipStream_t stream) {
    const float* xyz  = (const float*)d_in[0];
    const float* feat = (const float*)d_in[1];
    const float* W1   = (const float*)d_in[2];
    const float* b1   = (const float*)d_in[3];
    const float* W2   = (const float*)d_in[4];
    const float* b2   = (const float*)d_in[5];
    float* out = (float*)d_out;

    int* idx = (int*)d_ws;   // 2 MB

    knn_kernel<<<1024, 256, 0, stream>>>(xyz, idx);
    pm_kernel <<<512,  256, 0, stream>>>(feat, idx, W1, b1, W2, b2, out);
}

// Round 9
// 224.704 us; speedup vs baseline: 1.2127x; 1.2127x over previous
//
#include <hip/hip_runtime.h>
#include <math.h>

#define Bn 16
#define Gn 2048
#define Cn 128
#define Kn 16
#define SCAP 40    // u8 survivor slice cap per (query,sub); mean ~10.7, P(ovf)~1e-7

__device__ __forceinline__ float med3f(float a, float b, float c) {
#if __has_builtin(__builtin_amdgcn_fmed3f)
    return __builtin_amdgcn_fmed3f(a, b, c);
#else
    return fmaxf(fminf(a, b), fminf(fmaxf(a, b), c));
#endif
}

// BIT-IDENTICAL everywhere (self-consistent fp ranking incl. tie detection).
__device__ __forceinline__ float dist2(const float4 me, const float4 p) {
    float dot = fmaf(me.z, p.z, fmaf(me.y, p.y, me.x * p.x));
    return fmaf(-2.0f, dot, me.w + p.w);
}

__device__ __forceinline__ void ins16(float (&d)[16], float v) {
    float prev = d[0];
    d[0] = fminf(d[0], v);
    #pragma unroll
    for (int t = 1; t < 16; ++t) { float cur = d[t]; d[t] = med3f(v, prev, cur); prev = cur; }
}

__device__ __forceinline__ void bsort16(float (&x)[16]) {
    #pragma unroll
    for (int k = 8; k; k >>= 1) {
        #pragma unroll
        for (int t = 0; t < 16; ++t)
            if (!(t & k)) {
                float lo = fminf(x[t], x[t + k]);
                float hi = fmaxf(x[t], x[t + k]);
                x[t] = lo; x[t + k] = hi;
            }
    }
}

__device__ __forceinline__ void bmerge(float (&da)[16], const float (&db)[16]) {
    float x[16];
    #pragma unroll
    for (int t = 0; t < 16; ++t) x[t] = fminf(da[t], db[15 - t]);
    bsort16(x);
    #pragma unroll
    for (int t = 0; t < 16; ++t) da[t] = x[t];
}

__device__ __forceinline__ void merge8(float (&d)[16]) {
    #pragma unroll
    for (int m = 1; m < 8; m <<= 1) {
        float e[16];
        #pragma unroll
        for (int t = 0; t < 16; ++t) e[t] = __shfl_xor(d[t], m);
        float x[16];
        #pragma unroll
        for (int t = 0; t < 16; ++t) x[t] = fminf(d[t], e[15 - t]);
        bsort16(x);
        #pragma unroll
        for (int t = 0; t < 16; ++t) d[t] = x[t];
    }
}

// ---------------------------------------------------------------------------
// Kernel 1: KNN top-16 (unchanged): sample->filter->select, private u8 slices.
// ---------------------------------------------------------------------------
__global__ __launch_bounds__(256) void knn_kernel(const float* __restrict__ xyz,
                                                  int* __restrict__ idx_out) {
    __shared__ float4 pts[Gn];                      // 32 KB
    __shared__ unsigned char sbuf[256 * SCAP];      // 10 KB
    __shared__ int outb[32 * 16];                   // 2 KB
    __shared__ int tieb[32 * 16];                   // 2 KB

    const int x     = blockIdx.x;
    const int b     = (x & 7) | (((x >> 3) & 1) << 3);
    const int chunk = x >> 4;
    const int tid   = threadIdx.x;
    const int lane  = tid & 63;
    const int w     = tid >> 6;
    const int sub   = lane & 7;
    const int q     = w * 8 + (lane >> 3);
    const int g     = chunk * 32 + q;
    const int bs    = (w * 64 + lane) * SCAP;

    const float* xb = xyz + (size_t)b * Gn * 3;
    for (int i = tid; i < Gn; i += 256) {
        float px = xb[i * 3 + 0], py = xb[i * 3 + 1], pz = xb[i * 3 + 2];
        pts[i] = make_float4(px, py, pz, px * px + py * py + pz * pz);
    }
    __syncthreads();

    const float4 me = pts[g];
    const int base = sub << 8;
    const int c    = (37 * sub) & 255;

    float da[16], db[16];
    #pragma unroll
    for (int t = 0; t < 16; ++t) { da[t] = INFINITY; db[t] = INFINITY; }
    for (int j = 0; j < 48; j += 4) {
        float4 p0 = pts[base + ((j + 0 + c) & 255)];
        float4 p1 = pts[base + ((j + 1 + c) & 255)];
        float4 p2 = pts[base + ((j + 2 + c) & 255)];
        float4 p3 = pts[base + ((j + 3 + c) & 255)];
        float v0 = dist2(me, p0), v1 = dist2(me, p1);
        float v2 = dist2(me, p2), v3 = dist2(me, p3);
        ins16(da, v0); ins16(db, v1);
        ins16(da, v2); ins16(db, v3);
    }
    bmerge(da, db);
    merge8(da);
    const float T0 = da[15];

    int cnt = 0;
    for (int j = 0; j < 256; j += 4) {
        int m0 = (j + 0 + c) & 255;
        int m1 = (j + 1 + c) & 255;
        int m2 = (j + 2 + c) & 255;
        int m3 = (j + 3 + c) & 255;
        float v0 = dist2(me, pts[base + m0]);
        float v1 = dist2(me, pts[base + m1]);
        float v2 = dist2(me, pts[base + m2]);
        float v3 = dist2(me, pts[base + m3]);
        if (v0 <= T0) { if (cnt < SCAP) sbuf[bs + cnt] = (unsigned char)m0; cnt++; }
        if (v1 <= T0) { if (cnt < SCAP) sbuf[bs + cnt] = (unsigned char)m1; cnt++; }
        if (v2 <= T0) { if (cnt < SCAP) sbuf[bs + cnt] = (unsigned char)m2; cnt++; }
        if (v3 <= T0) { if (cnt < SCAP) sbuf[bs + cnt] = (unsigned char)m3; cnt++; }
    }
    const int S = (cnt > SCAP) ? SCAP : cnt;

    #pragma unroll
    for (int t = 0; t < 16; ++t) da[t] = INFINITY;
    for (int t = 0; t < S; ++t) {
        float4 p = pts[base + sbuf[bs + t]];
        ins16(da, dist2(me, p));
    }
    merge8(da);
    const float T = da[15];

    int maxc = S;
    #pragma unroll
    for (int m = 1; m < 8; m <<= 1) { int o = __shfl_xor(maxc, m); maxc = (o > maxc) ? o : maxc; }

    const unsigned lowm = (1u << sub) - 1;
    const int shft = lane & 56;
    int nl = 0, nt = 0;
    for (int t = 0; t < maxc; ++t) {
        bool act = (t < S);
        int h = act ? (base + sbuf[bs + t]) : 0;
        float v = dist2(me, pts[h]);
        bool pl = act && (v < T);
        bool pt = act && (v == T);
        unsigned long long ml = __ballot(pl);
        unsigned long long mt = __ballot(pt);
        unsigned gml = (unsigned)(ml >> shft) & 0xFFu;
        unsigned gmt = (unsigned)(mt >> shft) & 0xFFu;
        if (pl) outb[q * 16 + nl + __popc(gml & lowm)] = h;
        if (pt) { int pp = nt + __popc(gmt & lowm); if (pp < 16) tieb[q * 16 + pp] = h; }
        nl += __popc(gml);
        nt += __popc(gmt);
    }
    if (sub == 0) {
        int mfill = nl;
        int need  = 16 - mfill;
        int tc = (nt > 16) ? 16 : nt;
        for (int s = 0; s < need; ++s) {
            int best = 0x7fffffff, bp = -1;
            for (int u = 0; u < tc; ++u) {
                int vv = tieb[q * 16 + u];
                if (vv < best) { best = vv; bp = u; }
            }
            if (bp >= 0) { tieb[q * 16 + bp] = 0x7fffffff; outb[q * 16 + mfill + s] = best; }
        }
    }
    __syncthreads();

    int* op = idx_out + ((size_t)b * Gn + (size_t)chunk * 32) * Kn;
    for (int t = tid; t < 512; t += 256) op[t] = outb[t];
}

// ---------------------------------------------------------------------------
// Kernel 2: gather + L2 pool + 2-layer MLP with W tiles in LDS.
// 512 blocks x 64 rows; 256 thr; thread tile 4 rows x 8 cols.
// W tile (32k x 128) staged global->reg->LDS, reg-prefetch of next tile.
// Inner chunk: 4 A ds_read_b128 + 8 W ds_read_b128 + 128 v_fmac.
// ---------------------------------------------------------------------------
__device__ __forceinline__ float gelu_exact(float x) {
    return 0.5f * x * (1.0f + erff(x * 0.70710678118654752440f));
}

__global__ __launch_bounds__(256) void pm_kernel(const float* __restrict__ feat,
                                                 const int* __restrict__ idx,
                                                 const float* __restrict__ W1,
                                                 const float* __restrict__ b1,
                                                 const float* __restrict__ W2,
                                                 const float* __restrict__ b2,
                                                 float* __restrict__ out) {
    __shared__ float At[64 * 132];                  // 33.8 KB (pad 132)
    __shared__ float Wt[32 * 128];                  // 16 KB W tile
    __shared__ int   qidx[64 * 16];                 // 4 KB

    const int x     = blockIdx.x;                   // 0..511
    const int b     = (x & 7) | (((x >> 3) & 1) << 3);   // XCD-local feat batches
    const int chunk = x >> 4;                       // 0..31
    const int tid   = threadIdx.x;
    const int lane  = tid & 63;
    const int w     = tid >> 6;
    const size_t rowbase = (size_t)b * Gn + (size_t)chunk * 64;

    const int* ip = idx + rowbase * Kn;
    for (int t = tid; t < 1024; t += 256) qidx[t] = ip[t];
    __syncthreads();

    // ---- gather + pool: half-wave per query row, float4 lanes
    const float4* fb4 = (const float4*)(feat + (size_t)b * Gn * Cn);
    const int cl = lane & 31;
    for (int pass = 0; pass < 8; ++pass) {
        int qq = w * 16 + pass * 2 + (lane >> 5);   // 0..63
        float4 a = make_float4(0.f, 0.f, 0.f, 0.f);
        #pragma unroll
        for (int half = 0; half < 2; ++half) {
            int hs[8]; float4 f[8];
            #pragma unroll
            for (int k = 0; k < 8; ++k) hs[k] = qidx[qq * 16 + half * 8 + k];
            #pragma unroll
            for (int k = 0; k < 8; ++k) f[k] = fb4[(size_t)hs[k] * 32 + cl];
            #pragma unroll
            for (int k = 0; k < 8; ++k) {
                a.x = fmaf(f[k].x, f[k].x, a.x);
                a.y = fmaf(f[k].y, f[k].y, a.y);
                a.z = fmaf(f[k].z, f[k].z, a.z);
                a.w = fmaf(f[k].w, f[k].w, a.w);
            }
        }
        float4 r = make_float4(sqrtf(a.x), sqrtf(a.y), sqrtf(a.z), sqrtf(a.w));
        *(float4*)&At[qq * 132 + cl * 4] = r;
    }

    // ---- MLP thread mapping: j0 = col-group (8 cols), rg = row-group (4 rows)
    const int j0 = tid & 15;
    const int rg = tid >> 4;
    float acc[32];
    const float4* W1v = (const float4*)W1;
    const float4* W2v = (const float4*)W2;
    float4* Wt4 = (float4*)Wt;

    // stage W1 tile 0 (regs already in flight during gather epilogue)
    float4 wpre[4];
    #pragma unroll
    for (int u = 0; u < 4; ++u) wpre[u] = W1v[u * 256 + tid];
    __syncthreads();                                // gather At writes + qidx reads done
    #pragma unroll
    for (int u = 0; u < 4; ++u) Wt4[u * 256 + tid] = wpre[u];

    {   // bias init
        float4 ba = ((const float4*)b1)[j0 * 2];
        float4 bb = ((const float4*)b1)[j0 * 2 + 1];
        acc[0]=ba.x; acc[1]=ba.y; acc[2]=ba.z; acc[3]=ba.w;
        acc[4]=bb.x; acc[5]=bb.y; acc[6]=bb.z; acc[7]=bb.w;
        #pragma unroll
        for (int r = 1; r < 4; ++r)
            #pragma unroll
            for (int j = 0; j < 8; ++j) acc[r * 8 + j] = acc[j];
    }
    __syncthreads();                                // Wt tile 0 visible

    // ---- layer 1 ----
    #pragma unroll 1
    for (int t = 0; t < 4; ++t) {
        if (t < 3) {
            #pragma unroll
            for (int u = 0; u < 4; ++u) wpre[u] = W1v[(t + 1) * 1024 + u * 256 + tid];
        }
        #pragma unroll
        for (int k0 = 0; k0 < 32; k0 += 4) {
            float4 a4[4];
            #pragma unroll
            for (int r = 0; r < 4; ++r)
                a4[r] = *(const float4*)&At[(rg * 4 + r) * 132 + t * 32 + k0];
            float ar[4][4];
            #pragma unroll
            for (int r = 0; r < 4; ++r) { ar[r][0]=a4[r].x; ar[r][1]=a4[r].y; ar[r][2]=a4[r].z; ar[r][3]=a4[r].w; }
            #pragma unroll
            for (int kk = 0; kk < 4; ++kk) {
                float4 wl = *(const float4*)&Wt[(k0 + kk) * 128 + j0 * 8];
                float4 wh = *(const float4*)&Wt[(k0 + kk) * 128 + j0 * 8 + 4];
                #pragma unroll
                for (int r = 0; r < 4; ++r) {
                    acc[r*8+0] = fmaf(ar[r][kk], wl.x, acc[r*8+0]);
                    acc[r*8+1] = fmaf(ar[r][kk], wl.y, acc[r*8+1]);
                    acc[r*8+2] = fmaf(ar[r][kk], wl.z, acc[r*8+2]);
                    acc[r*8+3] = fmaf(ar[r][kk], wl.w, acc[r*8+3]);
                    acc[r*8+4] = fmaf(ar[r][kk], wh.x, acc[r*8+4]);
                    acc[r*8+5] = fmaf(ar[r][kk], wh.y, acc[r*8+5]);
                    acc[r*8+6] = fmaf(ar[r][kk], wh.z, acc[r*8+6]);
                    acc[r*8+7] = fmaf(ar[r][kk], wh.w, acc[r*8+7]);
                }
            }
        }
        __syncthreads();                            // tile reads done
        if (t < 3) {
            #pragma unroll
            for (int u = 0; u < 4; ++u) Wt4[u * 256 + tid] = wpre[u];
            __syncthreads();
        }
    }
    // all layer-1 At reads complete (final sync above) -> write h in place
    #pragma unroll
    for (int r = 0; r < 4; ++r) {
        float4 g0, g1;
        g0.x = gelu_exact(acc[r*8+0]); g0.y = gelu_exact(acc[r*8+1]);
        g0.z = gelu_exact(acc[r*8+2]); g0.w = gelu_exact(acc[r*8+3]);
        g1.x = gelu_exact(acc[r*8+4]); g1.y = gelu_exact(acc[r*8+5]);
        g1.z = gelu_exact(acc[r*8+6]); g1.w = gelu_exact(acc[r*8+7]);
        *(float4*)&At[(rg * 4 + r) * 132 + j0 * 8]     = g0;
        *(float4*)&At[(rg * 4 + r) * 132 + j0 * 8 + 4] = g1;
    }
    // stage W2 tile 0
    #pragma unroll
    for (int u = 0; u < 4; ++u) wpre[u] = W2v[u * 256 + tid];
    __syncthreads();                                // h writes visible; Wt free
    #pragma unroll
    for (int u = 0; u < 4; ++u) Wt4[u * 256 + tid] = wpre[u];
    {
        float4 ba = ((const float4*)b2)[j0 * 2];
        float4 bb = ((const float4*)b2)[j0 * 2 + 1];
        acc[0]=ba.x; acc[1]=ba.y; acc[2]=ba.z; acc[3]=ba.w;
        acc[4]=bb.x; acc[5]=bb.y; acc[6]=bb.z; acc[7]=bb.w;
        #pragma unroll
        for (int r = 1; r < 4; ++r)
            #pragma unroll
            for (int j = 0; j < 8; ++j) acc[r * 8 + j] = acc[j];
    }
    __syncthreads();

    // ---- layer 2 ----
    #pragma unroll 1
    for (int t = 0; t < 4; ++t) {
        if (t < 3) {
            #pragma unroll
            for (int u = 0; u < 4; ++u) wpre[u] = W2v[(t + 1) * 1024 + u * 256 + tid];
        }
        #pragma unroll
        for (int k0 = 0; k0 < 32; k0 += 4) {
            float4 a4[4];
            #pragma unroll
            for (int r = 0; r < 4; ++r)
                a4[r] = *(const float4*)&At[(rg * 4 + r) * 132 + t * 32 + k0];
            float ar[4][4];
            #pragma unroll
            for (int r = 0; r < 4; ++r) { ar[r][0]=a4[r].x; ar[r][1]=a4[r].y; ar[r][2]=a4[r].z; ar[r][3]=a4[r].w; }
            #pragma unroll
            for (int kk = 0; kk < 4; ++kk) {
                float4 wl = *(const float4*)&Wt[(k0 + kk) * 128 + j0 * 8];
                float4 wh = *(const float4*)&Wt[(k0 + kk) * 128 + j0 * 8 + 4];
                #pragma unroll
                for (int r = 0; r < 4; ++r) {
                    acc[r*8+0] = fmaf(ar[r][kk], wl.x, acc[r*8+0]);
                    acc[r*8+1] = fmaf(ar[r][kk], wl.y, acc[r*8+1]);
                    acc[r*8+2] = fmaf(ar[r][kk], wl.z, acc[r*8+2]);
                    acc[r*8+3] = fmaf(ar[r][kk], wl.w, acc[r*8+3]);
                    acc[r*8+4] = fmaf(ar[r][kk], wh.x, acc[r*8+4]);
                    acc[r*8+5] = fmaf(ar[r][kk], wh.y, acc[r*8+5]);
                    acc[r*8+6] = fmaf(ar[r][kk], wh.z, acc[r*8+6]);
                    acc[r*8+7] = fmaf(ar[r][kk], wh.w, acc[r*8+7]);
                }
            }
        }
        __syncthreads();
        if (t < 3) {
            #pragma unroll
            for (int u = 0; u < 4; ++u) Wt4[u * 256 + tid] = wpre[u];
            __syncthreads();
        }
    }

    float4* outv = (float4*)out;
    #pragma unroll
    for (int r = 0; r < 4; ++r) {
        size_t row = rowbase + rg * 4 + r;
        outv[row * 32 + j0 * 2]     = make_float4(acc[r*8+0], acc[r*8+1], acc[r*8+2], acc[r*8+3]);
        outv[row * 32 + j0 * 2 + 1] = make_float4(acc[r*8+4], acc[r*8+5], acc[r*8+6], acc[r*8+7]);
    }
}

// ---------------------------------------------------------------------------
extern "C" void kernel_launch(void* const* d_in, const int* in_sizes, int n_in,
                              void* d_out, int out_size, void* d_ws, size_t ws_size,
                              hipStream_t stream) {
    const float* xyz  = (const float*)d_in[0];
    const float* feat = (const float*)d_in[1];
    const float* W1   = (const float*)d_in[2];
    const float* b1   = (const float*)d_in[3];
    const float* W2   = (const float*)d_in[4];
    const float* b2   = (const float*)d_in[5];
    float* out = (float*)d_out;

    int* idx = (int*)d_ws;   // 2 MB

    knn_kernel<<<1024, 256, 0, stream>>>(xyz, idx);
    pm_kernel <<<512,  256, 0, stream>>>(feat, idx, W1, b1, W2, b2, out);
}